// Round 1
// baseline (1282.641 us; speedup 1.0000x reference)
//
#include <hip/hip_runtime.h>

// NeuralHMM forward pass, B=32, T=4096, K=16, fp32.
// Outputs (flat, in order): beliefs[B,T,K], log_beliefs[B,T,K],
//                           log_normalizers[B,T], A[B,T,K,K]
//
// Strategy:
//  - blocks 0..7   : forward scan, 1 wave per batch (4 waves/block).
//                    Recursion in PROBABILITY space: P' = normalize((P @ A') * exp(em)).
//                    A' = row-normalized tridiagonal with 1e-10 in the zero slots
//                    (matches jnp.log(clip(A,1e-10)) semantics). Leak term folded
//                    into FMA coefficients using sum(P)=1.
//                    Lane layout: j = lane & 15 (rows of 16 replicated across the
//                    wave); neighbor access + reduction via DPP (no LDS).
//  - blocks 8..    : A writer, one float4 per thread (memory-bound, ~134 MB).

#define BB 32
#define TT 4096
#define KK 16

constexpr float RHO  = 0.001f;
constexpr float LEAK = 1e-10f;

template<int CTRL>
__device__ __forceinline__ float dppf(float x) {
  return __uint_as_float((unsigned)__builtin_amdgcn_update_dpp(
      0, (int)__float_as_uint(x), CTRL, 0xF, 0xF, true));
}

// sum across the 16-lane row (all 16 lanes get the total)
__device__ __forceinline__ float sum16(float x) {
  x += dppf<0xB1>(x);   // quad_perm [1,0,3,2]  : xor 1
  x += dppf<0x4E>(x);   // quad_perm [2,3,0,1]  : xor 2
  x += dppf<0x141>(x);  // row_half_mirror      : xor 7
  x += dppf<0x140>(x);  // row_mirror           : xor 15
  return x;
}

__global__ __launch_bounds__(256) void hmm_kernel(
    const float* __restrict__ em,   // [B,T,K]
    const float* __restrict__ bp,   // [B,T]
    const float* __restrict__ msk,  // [B,T]
    float* __restrict__ out)
{
  const long BTK = (long)BB * TT * KK;
  float* beliefs = out;
  float* logb    = out + BTK;
  float* lzs     = out + 2 * BTK;
  float* Aout    = out + 2 * BTK + (long)BB * TT;

  const int bid = blockIdx.x;

  if (bid >= 8) {
    // ---------------- A writer: one float4 per thread ----------------
    long tid  = (long)(bid - 8) * 256 + threadIdx.x;   // 8388608 threads exactly
    long flat = tid * 4;                               // element index into A
    int  bt   = (int)(flat >> 8);
    int  rem  = (int)(flat & 255);
    int  r    = rem >> 4;
    int  c0   = rem & 15;
    float p   = bp[bt];
    float eta = fminf(fmaxf(0.02f + 0.33f * p, 0.001f), 0.95f);
    float diag, s;
    if (r == 0)       { diag = 1.0f - eta; s = (1.0f - eta) + eta; }
    else if (r == 15) { diag = 1.0f - RHO; s = RHO + (1.0f - RHO); }
    else { diag = fmaxf((1.0f - eta) - RHO, 0.01f); s = (RHO + diag) + eta; }
    s = fmaxf(s, 1e-8f);
    float inv = 1.0f / s;
    float4 v;
    float* vp = &v.x;
    #pragma unroll
    for (int q = 0; q < 4; ++q) {
      int c = c0 + q;
      float a = (c == r) ? diag : (c == r + 1) ? eta : (c == r - 1) ? RHO : 0.0f;
      vp[q] = a * inv;
    }
    ((float4*)Aout)[tid] = v;
    return;
  }

  // ---------------- forward scan: one wave per batch ----------------
  const int wave = threadIdx.x >> 6;
  const int lane = threadIdx.x & 63;
  const int j    = lane & 15;
  const int b    = bid * 4 + wave;

  const float* emb = em  + (long)b * TT * KK;
  const float* bpb = bp  + (long)b * TT;
  const float* mb  = msk + (long)b * TT;
  float* belb = beliefs + (long)b * TT * KK;
  float* lbb  = logb    + (long)b * TT * KK;
  float* lzb  = lzs     + (long)b * TT;

  // ---- t = 0 (closed form, log space; alpha0 = [0, -1e6, ...]) ----
  float em0  = emb[j];
  float em00 = __uint_as_float(
      (unsigned)__builtin_amdgcn_readfirstlane((int)__float_as_uint(em0)));
  float m0      = mb[0];
  float la_init = (j == 0) ? 0.0f : -1000000.0f;
  // lZ0 = logsumexp(alpha0 + em) = em[0] exactly in fp32 (others underflow)
  float la0new  = (la_init + em0) - em00;
  float la0     = m0 * la0new + (1.0f - m0) * la_init;
  float P       = __expf(la0);   // [1, 0, 0, ...] (exp(-1e6) -> 0)

  if (lane < 16) {
    belb[j] = P;
    lbb[j]  = la0;
    if (j == 0) lzb[0] = m0 * em00;
  }

  // ---- one recursion step in probability space ----
  auto step = [&](float emt, float bpt, float mt, int t) {
    float eta = fminf(fmaxf(0.02f + 0.33f * bpt, 0.001f), 0.95f);
    float dm  = fmaxf((1.0f - eta) - RHO, 0.01f);
    float s0  = (1.0f - eta) + eta;
    float sm  = (RHO + dm) + eta;
    float s15 = RHO + (1.0f - RHO);
    // column-j coefficients (divisor = source row's normalizer)
    float s_jm1  = (j == 1) ? s0 : sm;                         // row j-1
    float s_j    = (j == 0) ? s0 : ((j == 15) ? s15 : sm);     // row j
    float s_jp1  = (j == 14) ? s15 : sm;                       // row j+1
    float diag_j = (j == 0) ? (1.0f - eta) : ((j == 15) ? (1.0f - RHO) : dm);
    // fold the 1e-10 leak (uses sum(P)=1): pred = LEAK + sum band_i * (c_i - LEAK)
    float cL = eta    / s_jm1 - LEAK;   // from P[j-1] (super-diagonal of row j-1)
    float cD = diag_j / s_j   - LEAK;
    float cR = RHO    / s_jp1 - LEAK;   // from P[j+1] (sub-diagonal of row j+1)
    float E  = __expf(emt);             // independent of P -> off critical path

    float pl = dppf<0x111>(P);          // row_shr:1 -> P[j-1], 0 at j==0
    float pr = dppf<0x101>(P);          // row_shl:1 -> P[j+1], 0 at j==15
    float pred = fmaf(pl, cL, fmaf(P, cD, fmaf(pr, cR, LEAK)));
    float u  = pred * E;
    float S  = sum16(u);
    float Pn = u * __builtin_amdgcn_rcpf(S);
    bool on  = (mt != 0.0f);
    P = on ? Pn : P;
    if (lane < 16) {
      belb[(long)t * KK + j] = P;
      lbb[(long)t * KK + j]  = __logf(P);
      if (j == 0) lzb[t] = on ? __logf(S) : 0.0f;
    }
  };

  // ---- main loop t = 1..T-1, 16-deep software load pipeline ----
  constexpr int U = 16;
  float emv[U], bpv[U], mv[U];
  #pragma unroll
  for (int i = 0; i < U; ++i) {
    int t = 1 + i;
    emv[i] = emb[(long)t * KK + j];
    bpv[i] = bpb[t];
    mv[i]  = mb[t];
  }
  for (int t0 = 1; t0 < TT; t0 += U) {
    float emn[U], bpn[U], mn[U];
    const int tn0 = t0 + U;
    #pragma unroll
    for (int i = 0; i < U; ++i) {          // issue next block's loads first
      int t  = tn0 + i;
      int ts = (t < TT) ? t : (TT - 1);
      emn[i] = emb[(long)ts * KK + j];
      bpn[i] = bpb[ts];
      mn[i]  = mb[ts];
    }
    #pragma unroll
    for (int i = 0; i < U; ++i) {
      int t = t0 + i;
      if (t < TT) step(emv[i], bpv[i], mv[i], t);
    }
    #pragma unroll
    for (int i = 0; i < U; ++i) { emv[i] = emn[i]; bpv[i] = bpn[i]; mv[i] = mn[i]; }
  }
}

extern "C" void kernel_launch(void* const* d_in, const int* in_sizes, int n_in,
                              void* d_out, int out_size, void* d_ws, size_t ws_size,
                              hipStream_t stream) {
  const float* em = (const float*)d_in[0];
  const float* bp = (const float*)d_in[1];
  const float* mk = (const float*)d_in[2];
  float* out = (float*)d_out;
  // 8 scan blocks + 32768 A-writer blocks (8388608 threads, float4 each)
  dim3 grid(8 + 32768), block(256);
  hipLaunchKernelGGL(hmm_kernel, grid, block, 0, stream, em, bp, mk, out);
}

// Round 2
// 238.839 us; speedup vs baseline: 5.3703x; 5.3703x over previous
//
#include <hip/hip_runtime.h>

// NeuralHMM forward, B=32, T=4096, K=16, fp32.
// Outputs flat: beliefs[B,T,K], log_beliefs[B,T,K], log_normalizers[B,T], A[B,T,K,K]
//
// Chunked parallel scan (4 kernels, stream-serialized):
//  K1: compose per-chunk 16x16 transfer matrices G (chunks of L=64 steps), parallel
//      over (b,chunk). G stashed in beliefs region of d_out (overwritten by K3).
//  K2: serial scan over 64 chunk operators per batch -> P_start vectors
//      (stashed in first 128KB of A region, overwritten by K4).
//  K3: replay each chunk from P_start (verified round-1 step math), writes
//      beliefs / log_beliefs / log_normalizers.
//  K4: A writer (verified round-1 code), runs last.

#define BB 32
#define TT 4096
#define KK 16
#define LCH 64
#define NCH 64   // NCH*LCH == TT

constexpr float RHO  = 0.001f;
constexpr float LEAK = 1e-10f;

template<int CTRL>
__device__ __forceinline__ float dppf(float x) {
  return __uint_as_float((unsigned)__builtin_amdgcn_update_dpp(
      0, (int)__float_as_uint(x), CTRL, 0xF, 0xF, true));
}
// sum across each 16-lane row (all lanes get the row total)
__device__ __forceinline__ float sum16(float x) {
  x += dppf<0xB1>(x);   // xor 1
  x += dppf<0x4E>(x);   // xor 2
  x += dppf<0x141>(x);  // xor 7 (row_half_mirror)
  x += dppf<0x140>(x);  // xor 15 (row_mirror)
  return x;
}
__device__ __forceinline__ float rdfirst(float x) {
  return __uint_as_float((unsigned)__builtin_amdgcn_readfirstlane((int)__float_as_uint(x)));
}

struct Coefs { float cL, cD, cR, E; };

// column-j coefficients of M_t = D(E) A'^T (leak folded: band coef minus LEAK)
__device__ __forceinline__ Coefs make_coefs(int j, float bpt, float emt) {
  float eta = fminf(fmaxf(fmaf(0.33f, bpt, 0.02f), 0.001f), 0.95f);
  float dm  = fmaxf((1.0f - eta) - RHO, 0.01f);
  float s0  = (1.0f - eta) + eta;
  float sm  = (RHO + dm) + eta;
  float s15 = RHO + (1.0f - RHO);
  float i0  = __builtin_amdgcn_rcpf(s0);
  float im  = __builtin_amdgcn_rcpf(sm);
  float i15 = __builtin_amdgcn_rcpf(s15);
  float i_jm1 = (j == 1) ? i0 : im;                       // row j-1 normalizer
  float i_j   = (j == 0) ? i0 : ((j == 15) ? i15 : im);
  float i_jp1 = (j == 14) ? i15 : im;                     // row j+1 normalizer
  float diag  = (j == 0) ? (1.0f - eta) : ((j == 15) ? (1.0f - RHO) : dm);
  Coefs c;
  c.cL = fmaf(eta,  i_jm1, -LEAK);
  c.cD = fmaf(diag, i_j,   -LEAK);
  c.cR = fmaf(RHO,  i_jp1, -LEAK);
  c.E  = __expf(emt);
  return c;
}

// ---------------- K1: chunk operator composition ----------------
// wave (b,c): R := M_last ... M_first (c in 0..NCH-2), rescaled per step.
// lane = 16g+j holds R[j][4g..4g+3].
__global__ __launch_bounds__(256) void phase1_kernel(
    const float* __restrict__ em, const float* __restrict__ bp,
    const float* __restrict__ msk, float* __restrict__ Gbuf)
{
  int wid  = blockIdx.x * 4 + (threadIdx.x >> 6);
  int lane = threadIdx.x & 63;
  int g = lane >> 4, j = lane & 15;
  int b = wid & 31;
  int c = wid >> 5;                       // 0..62
  long t0 = (long)c * LCH + 1;
  const float* emb = em  + ((long)b * TT + t0) * KK;
  const float* bpb = bp  + (long)b * TT + t0;
  const float* mb  = msk + (long)b * TT + t0;

  float r0 = (j == 4*g + 0) ? 1.0f : 0.0f;
  float r1 = (j == 4*g + 1) ? 1.0f : 0.0f;
  float r2 = (j == 4*g + 2) ? 1.0f : 0.0f;
  float r3 = (j == 4*g + 3) ? 1.0f : 0.0f;

  float em_c = emb[j], bp_c = bpb[0], m_c = mb[0];
  for (int s = 0; s < LCH; ++s) {
    int sn = (s + 1 < LCH) ? s + 1 : s;
    float em_n = emb[(long)sn * KK + j];
    float bp_n = bpb[sn];
    float m_n  = mb[sn];

    Coefs cf = make_coefs(j, bp_c, em_c);
    bool on  = (m_c != 0.0f);
    float cL = on ? cf.cL : 0.0f;
    float cD = on ? cf.cD : 1.0f;
    float cR = on ? cf.cR : 0.0f;
    float lk = on ? LEAK  : 0.0f;
    float E  = on ? cf.E  : 1.0f;

    // column sums (pre-update), grand total for rescale
    float S0 = sum16(r0), S1 = sum16(r1), S2 = sum16(r2), S3 = sum16(r3);
    float part = (S0 + S1) + (S2 + S3);
    part += __shfl_xor(part, 16);
    part += __shfl_xor(part, 32);
    float Es = E * __builtin_amdgcn_rcpf(part);

    float pl0 = dppf<0x111>(r0), pr0 = dppf<0x101>(r0);
    float pl1 = dppf<0x111>(r1), pr1 = dppf<0x101>(r1);
    float pl2 = dppf<0x111>(r2), pr2 = dppf<0x101>(r2);
    float pl3 = dppf<0x111>(r3), pr3 = dppf<0x101>(r3);
    r0 = Es * fmaf(pl0, cL, fmaf(r0, cD, fmaf(pr0, cR, lk * S0)));
    r1 = Es * fmaf(pl1, cL, fmaf(r1, cD, fmaf(pr1, cR, lk * S1)));
    r2 = Es * fmaf(pl2, cL, fmaf(r2, cD, fmaf(pr2, cR, lk * S2)));
    r3 = Es * fmaf(pl3, cL, fmaf(r3, cD, fmaf(pr3, cR, lk * S3)));

    em_c = em_n; bp_c = bp_n; m_c = m_n;
  }
  float4 v; v.x = r0; v.y = r1; v.z = r2; v.w = r3;
  ((float4*)(Gbuf + ((long)(b * NCH + c) << 8)))[j * 4 + g] = v;
}

// ---------------- K2: chunk-level serial scan ----------------
// wave per batch. P_start[b,c] = normalized alpha at t = 64c.
__global__ __launch_bounds__(256) void phase2_kernel(
    const float* __restrict__ em, const float* __restrict__ msk,
    const float* __restrict__ Gbuf, float* __restrict__ Pst)
{
  int b    = blockIdx.x * 4 + (threadIdx.x >> 6);  // 0..31
  int lane = threadIdx.x & 63;
  int g = lane >> 4, j = lane & 15;

  // t = 0 init (closed form, matches round-1 verified code)
  float em0  = em[(long)b * TT * KK + j];
  float em00 = rdfirst(em0);
  float m0   = msk[(long)b * TT];
  float la_init = (j == 0) ? 0.0f : -1000000.0f;
  float la0 = m0 * ((la_init + em0) - em00) + (1.0f - m0) * la_init;
  float P   = __expf(la0);

  const int src = 20 * g;   // lane 16g + (4g+q)
  float4 grow = *((const float4*)(Gbuf + ((long)(b * NCH) << 8)) + (j * 4 + g));
  for (int c = 0; c < NCH; ++c) {
    if (lane < 16) Pst[((long)(b * NCH + c) << 4) + j] = P;
    if (c == NCH - 1) break;
    float4 gnext = grow;
    if (c + 1 < NCH - 1)
      gnext = *((const float4*)(Gbuf + ((long)(b * NCH + c + 1) << 8)) + (j * 4 + g));
    float p0 = __shfl(P, src + 0), p1 = __shfl(P, src + 1);
    float p2 = __shfl(P, src + 2), p3 = __shfl(P, src + 3);
    float up = grow.x * p0;
    up = fmaf(grow.y, p1, up);
    up = fmaf(grow.z, p2, up);
    up = fmaf(grow.w, p3, up);
    up += __shfl_xor(up, 16);
    up += __shfl_xor(up, 32);        // u_j replicated on all lanes
    float S = sum16(up);
    P = up * __builtin_amdgcn_rcpf(S);
    grow = gnext;
  }
}

// ---------------- K3: per-chunk replay, emit outputs ----------------
__global__ __launch_bounds__(256) void phase3_kernel(
    const float* __restrict__ em, const float* __restrict__ bp,
    const float* __restrict__ msk, const float* __restrict__ Pst,
    float* __restrict__ out)
{
  const long BTK = (long)BB * TT * KK;
  float* beliefs = out;
  float* logb    = out + BTK;
  float* lzs     = out + 2 * BTK;

  int wid  = blockIdx.x * 4 + (threadIdx.x >> 6);
  int lane = threadIdx.x & 63;
  int j = lane & 15;
  int b = wid & 31;
  int c = wid >> 5;                      // 0..63

  const float* emb = em  + (long)b * TT * KK;
  const float* bpb = bp  + (long)b * TT;
  const float* mb  = msk + (long)b * TT;
  float* belb = beliefs + (long)b * TT * KK;
  float* lbb  = logb    + (long)b * TT * KK;
  float* lzb  = lzs     + (long)b * TT;

  float P = Pst[((long)(b * NCH + c) << 4) + j];

  if (c == 0) {
    float em0  = emb[j];
    float em00 = rdfirst(em0);
    float m0   = mb[0];
    float la_init = (j == 0) ? 0.0f : -1000000.0f;
    float la0 = m0 * ((la_init + em0) - em00) + (1.0f - m0) * la_init;
    if (lane < 16) {
      belb[j] = P;
      lbb[j]  = la0;
      if (j == 0) lzb[0] = m0 * em00;
    }
  }

  int t0 = c * LCH + 1;
  int t1 = (t0 + LCH - 1 < TT - 1) ? (t0 + LCH - 1) : (TT - 1);

  float em_c = emb[(long)t0 * KK + j], bp_c = bpb[t0], m_c = mb[t0];
  for (int t = t0; t <= t1; ++t) {
    int tn = (t + 1 <= t1) ? t + 1 : t;
    float em_n = emb[(long)tn * KK + j];
    float bp_n = bpb[tn];
    float m_n  = mb[tn];

    Coefs cf = make_coefs(j, bp_c, em_c);
    float pl = dppf<0x111>(P), pr = dppf<0x101>(P);
    float pred = fmaf(pl, cf.cL, fmaf(P, cf.cD, fmaf(pr, cf.cR, LEAK)));
    float u = pred * cf.E;
    float S = sum16(u);
    float Pn = u * __builtin_amdgcn_rcpf(S);
    bool on = (m_c != 0.0f);
    P = on ? Pn : P;
    if (lane < 16) {
      belb[(long)t * KK + j] = P;
      lbb[(long)t * KK + j]  = __logf(P);
      if (j == 0) lzb[t] = on ? __logf(S) : 0.0f;
    }
    em_c = em_n; bp_c = bp_n; m_c = m_n;
  }
}

// ---------------- K4: A writer (verified round-1 code) ----------------
__global__ __launch_bounds__(256) void a_writer_kernel(
    const float* __restrict__ bp, float* __restrict__ Aout)
{
  long tid  = (long)blockIdx.x * 256 + threadIdx.x;  // 8388608 threads
  long flat = tid * 4;
  int  bt   = (int)(flat >> 8);
  int  rem  = (int)(flat & 255);
  int  r    = rem >> 4;
  int  c0   = rem & 15;
  float p   = bp[bt];
  float eta = fminf(fmaxf(0.02f + 0.33f * p, 0.001f), 0.95f);
  float diag, s;
  if (r == 0)       { diag = 1.0f - eta; s = (1.0f - eta) + eta; }
  else if (r == 15) { diag = 1.0f - RHO; s = RHO + (1.0f - RHO); }
  else { diag = fmaxf((1.0f - eta) - RHO, 0.01f); s = (RHO + diag) + eta; }
  s = fmaxf(s, 1e-8f);
  float inv = 1.0f / s;
  float4 v;
  float* vp = &v.x;
  #pragma unroll
  for (int q = 0; q < 4; ++q) {
    int cc = c0 + q;
    float a = (cc == r) ? diag : (cc == r + 1) ? eta : (cc == r - 1) ? RHO : 0.0f;
    vp[q] = a * inv;
  }
  ((float4*)Aout)[tid] = v;
}

extern "C" void kernel_launch(void* const* d_in, const int* in_sizes, int n_in,
                              void* d_out, int out_size, void* d_ws, size_t ws_size,
                              hipStream_t stream) {
  const float* em = (const float*)d_in[0];
  const float* bp = (const float*)d_in[1];
  const float* mk = (const float*)d_in[2];
  float* out = (float*)d_out;

  const long BTK = (long)BB * TT * KK;
  float* Gbuf = out;                         // stash G in beliefs region (2MB < 8MB)
  float* Aout = out + 2 * BTK + (long)BB * TT;
  float* Pst  = Aout;                        // stash P_start in A corner (128KB)

  hipLaunchKernelGGL(phase1_kernel, dim3(504),   dim3(256), 0, stream, em, bp, mk, Gbuf);
  hipLaunchKernelGGL(phase2_kernel, dim3(8),     dim3(256), 0, stream, em, mk, Gbuf, Pst);
  hipLaunchKernelGGL(phase3_kernel, dim3(512),   dim3(256), 0, stream, em, bp, mk, Pst, out);
  hipLaunchKernelGGL(a_writer_kernel, dim3(32768), dim3(256), 0, stream, bp, Aout);
}

// Round 3
// 205.553 us; speedup vs baseline: 6.2400x; 1.1619x over previous
//
#include <hip/hip_runtime.h>

// NeuralHMM forward, B=32, T=4096, K=16, fp32.
// Outputs flat: beliefs[B,T,K], log_beliefs[B,T,K], log_normalizers[B,T], A[B,T,K,K]
//
// Chunked parallel scan:
//  K1: per-chunk 16x16 transfer operators G (LEAK DROPPED — error ~1e-7 rel,
//      restored by K3's per-step leak; rescale every 4 steps for fp32 range).
//  K2: serial scan over 64 chunk operators per batch -> P_start (verified r2 code).
//  K3: replay, 4 DISTINCT chunks per wave (one per 16-lane row; DPP ops are
//      row-local), depth-4 load pipeline. Writes beliefs/log_beliefs/log_norm.
//  K4: A writer (verified r1 code), runs last (overwrites the P_start stash).

#define BB 32
#define TT 4096
#define KK 16
#define LCH 64
#define NCH 64

constexpr float RHO  = 0.001f;
constexpr float LEAK = 1e-10f;

template<int CTRL>
__device__ __forceinline__ float dppf(float x) {
  return __uint_as_float((unsigned)__builtin_amdgcn_update_dpp(
      0, (int)__float_as_uint(x), CTRL, 0xF, 0xF, true));
}
// sum across each 16-lane row (row-local; all lanes get the row total)
__device__ __forceinline__ float sum16(float x) {
  x += dppf<0xB1>(x);   // xor 1
  x += dppf<0x4E>(x);   // xor 2
  x += dppf<0x141>(x);  // xor 7
  x += dppf<0x140>(x);  // xor 15
  return x;
}
__device__ __forceinline__ float rdfirst(float x) {
  return __uint_as_float((unsigned)__builtin_amdgcn_readfirstlane((int)__float_as_uint(x)));
}

// ---------------- K1: chunk operator composition (leak-free) ----------------
// wave (b,c): R := M_last ... M_first, c in 0..NCH-2. lane 16g+j holds R[j][4g+q].
__global__ __launch_bounds__(256) void phase1_kernel(
    const float* __restrict__ em, const float* __restrict__ bp,
    const float* __restrict__ msk, float* __restrict__ Gbuf)
{
  int wid  = blockIdx.x * 4 + (threadIdx.x >> 6);
  int lane = threadIdx.x & 63;
  int g = lane >> 4, j = lane & 15;
  int b = wid & 31;
  int c = wid >> 5;                       // 0..62
  long t0 = (long)c * LCH + 1;
  const float* emb = em  + ((long)b * TT + t0) * KK;
  const float* bpb = bp  + (long)b * TT + t0;
  const float* mb  = msk + (long)b * TT + t0;

  float r0 = (j == 4*g + 0) ? 1.0f : 0.0f;
  float r1 = (j == 4*g + 1) ? 1.0f : 0.0f;
  float r2 = (j == 4*g + 2) ? 1.0f : 0.0f;
  float r3 = (j == 4*g + 3) ? 1.0f : 0.0f;

  float emv[4], bpv[4], mv[4];
  #pragma unroll
  for (int k = 0; k < 4; ++k) {
    emv[k] = emb[(long)k * KK + j]; bpv[k] = bpb[k]; mv[k] = mb[k];
  }
  for (int s0 = 0; s0 < LCH; s0 += 4) {
    float emn[4], bpn[4], mn[4];
    #pragma unroll
    for (int k = 0; k < 4; ++k) {
      int sn = s0 + 4 + k; if (sn > LCH - 1) sn = LCH - 1;
      emn[k] = emb[(long)sn * KK + j]; bpn[k] = bpb[sn]; mn[k] = mb[sn];
    }
    #pragma unroll
    for (int k = 0; k < 4; ++k) {
      float eta = fminf(fmaxf(fmaf(0.33f, bpv[k], 0.02f), 0.001f), 0.95f);
      float dm  = fmaxf((1.0f - eta) - RHO, 0.01f);
      float s0n = (1.0f - eta) + eta;
      float smn = (RHO + dm) + eta;
      float i0  = __builtin_amdgcn_rcpf(s0n);
      float im  = __builtin_amdgcn_rcpf(smn);
      float i_jm1 = (j == 1) ? i0 : im;
      float i_j   = (j == 0) ? i0 : ((j == 15) ? 1.0f : im);
      float i_jp1 = (j == 14) ? 1.0f : im;
      float diag  = (j == 0) ? (1.0f - eta) : ((j == 15) ? (1.0f - RHO) : dm);
      bool on  = (mv[k] != 0.0f);
      float cL = on ? eta  * i_jm1 : 0.0f;
      float cD = on ? diag * i_j   : 1.0f;
      float cR = on ? RHO  * i_jp1 : 0.0f;
      float E  = on ? __expf(emv[k]) : 1.0f;

      float pl0 = dppf<0x111>(r0), pr0 = dppf<0x101>(r0);
      float pl1 = dppf<0x111>(r1), pr1 = dppf<0x101>(r1);
      float pl2 = dppf<0x111>(r2), pr2 = dppf<0x101>(r2);
      float pl3 = dppf<0x111>(r3), pr3 = dppf<0x101>(r3);
      r0 = E * fmaf(pl0, cL, fmaf(r0, cD, pr0 * cR));
      r1 = E * fmaf(pl1, cL, fmaf(r1, cD, pr1 * cR));
      r2 = E * fmaf(pl2, cL, fmaf(r2, cD, pr2 * cR));
      r3 = E * fmaf(pl3, cL, fmaf(r3, cD, pr3 * cR));
    }
    // range-control rescale (every 4 steps; growth <= e^22 between rescales)
    float grand = sum16((r0 + r1) + (r2 + r3));
    grand += __shfl_xor(grand, 16);
    grand += __shfl_xor(grand, 32);
    float sc = __builtin_amdgcn_rcpf(grand);
    r0 *= sc; r1 *= sc; r2 *= sc; r3 *= sc;
    #pragma unroll
    for (int k = 0; k < 4; ++k) { emv[k] = emn[k]; bpv[k] = bpn[k]; mv[k] = mn[k]; }
  }
  float4 v; v.x = r0; v.y = r1; v.z = r2; v.w = r3;
  ((float4*)(Gbuf + ((long)(b * NCH + c) << 8)))[j * 4 + g] = v;
}

// ---------------- K2: chunk-level serial scan (verified r2) ----------------
__global__ __launch_bounds__(256) void phase2_kernel(
    const float* __restrict__ em, const float* __restrict__ msk,
    const float* __restrict__ Gbuf, float* __restrict__ Pst)
{
  int b    = blockIdx.x * 4 + (threadIdx.x >> 6);  // 0..31
  int lane = threadIdx.x & 63;
  int g = lane >> 4, j = lane & 15;

  float em0  = em[(long)b * TT * KK + j];
  float em00 = rdfirst(em0);
  float m0   = msk[(long)b * TT];
  float la_init = (j == 0) ? 0.0f : -1000000.0f;
  float la0 = m0 * ((la_init + em0) - em00) + (1.0f - m0) * la_init;
  float P   = __expf(la0);

  const int src = 20 * g;   // lane 16g+j pulls p_{4g+q}
  float4 grow = *((const float4*)(Gbuf + ((long)(b * NCH) << 8)) + (j * 4 + g));
  for (int c = 0; c < NCH; ++c) {
    if (lane < 16) Pst[((long)(b * NCH + c) << 4) + j] = P;
    if (c == NCH - 1) break;
    float4 gnext = grow;
    if (c + 1 < NCH - 1)
      gnext = *((const float4*)(Gbuf + ((long)(b * NCH + c + 1) << 8)) + (j * 4 + g));
    float p0 = __shfl(P, src + 0), p1 = __shfl(P, src + 1);
    float p2 = __shfl(P, src + 2), p3 = __shfl(P, src + 3);
    float up = grow.x * p0;
    up = fmaf(grow.y, p1, up);
    up = fmaf(grow.z, p2, up);
    up = fmaf(grow.w, p3, up);
    up += __shfl_xor(up, 16);
    up += __shfl_xor(up, 32);
    float S = sum16(up);
    P = up * __builtin_amdgcn_rcpf(S);
    grow = gnext;
  }
}

// ---------------- K3: replay, 4 distinct chunks per wave ----------------
__global__ __launch_bounds__(256) void phase3_kernel(
    const float* __restrict__ em, const float* __restrict__ bp,
    const float* __restrict__ msk, const float* __restrict__ Pst,
    float* __restrict__ out)
{
  const long BTK = (long)BB * TT * KK;
  float* beliefs = out;
  float* logb    = out + BTK;
  float* lzs     = out + 2 * BTK;

  int wid  = blockIdx.x * 4 + (threadIdx.x >> 6);   // 0..511
  int lane = threadIdx.x & 63;
  int j   = lane & 15;
  int row = lane >> 4;
  int b   = wid >> 4;                               // 0..31
  int c   = ((wid & 15) << 2) + row;                // 0..63 (per-row chunk)

  const float* emb = em  + (long)b * TT * KK;
  const float* bpb = bp  + (long)b * TT;
  const float* mb  = msk + (long)b * TT;
  float* belb = beliefs + (long)b * TT * KK;
  float* lbb  = logb    + (long)b * TT * KK;
  float* lzb  = lzs     + (long)b * TT;

  float P = Pst[((long)(b * NCH + c) << 4) + j];

  if (c == 0) {                                     // only lanes 0..15 of wid%16==0
    float em0  = emb[j];
    float em00 = rdfirst(em0);
    float m0   = mb[0];
    float la_init = (j == 0) ? 0.0f : -1000000.0f;
    float la0 = m0 * ((la_init + em0) - em00) + (1.0f - m0) * la_init;
    belb[j] = P;
    lbb[j]  = la0;
    if (j == 0) lzb[0] = m0 * em00;
  }

  const int t0 = (c << 6) + 1;                      // 64 steps; c==63 row: 63 valid
  float emv[4], bpv[4], mv[4];
  #pragma unroll
  for (int k = 0; k < 4; ++k) {
    int ts = t0 + k; if (ts > TT - 1) ts = TT - 1;
    emv[k] = emb[(long)ts * KK + j]; bpv[k] = bpb[ts]; mv[k] = mb[ts];
  }
  for (int i0 = 0; i0 < LCH; i0 += 4) {
    float emn[4], bpn[4], mn[4];
    #pragma unroll
    for (int k = 0; k < 4; ++k) {
      int ts = t0 + i0 + 4 + k; if (ts > TT - 1) ts = TT - 1;
      emn[k] = emb[(long)ts * KK + j]; bpn[k] = bpb[ts]; mn[k] = mb[ts];
    }
    #pragma unroll
    for (int k = 0; k < 4; ++k) {
      int t = t0 + i0 + k;
      float eta = fminf(fmaxf(fmaf(0.33f, bpv[k], 0.02f), 0.001f), 0.95f);
      float dm  = fmaxf((1.0f - eta) - RHO, 0.01f);
      float s0n = (1.0f - eta) + eta;
      float smn = (RHO + dm) + eta;
      float i0r = __builtin_amdgcn_rcpf(s0n);
      float im  = __builtin_amdgcn_rcpf(smn);
      float i_jm1 = (j == 1) ? i0r : im;
      float i_j   = (j == 0) ? i0r : ((j == 15) ? 1.0f : im);
      float i_jp1 = (j == 14) ? 1.0f : im;
      float diag  = (j == 0) ? (1.0f - eta) : ((j == 15) ? (1.0f - RHO) : dm);
      float cL = fmaf(eta,  i_jm1, -LEAK);
      float cD = fmaf(diag, i_j,   -LEAK);
      float cR = fmaf(RHO,  i_jp1, -LEAK);
      float E  = __expf(emv[k]);

      float pl = dppf<0x111>(P), pr = dppf<0x101>(P);
      float pred = fmaf(pl, cL, fmaf(P, cD, fmaf(pr, cR, LEAK)));
      float u = pred * E;
      float S = sum16(u);
      float Pn = u * __builtin_amdgcn_rcpf(S);
      bool on = (mv[k] != 0.0f);
      if (t < TT) {
        P = on ? Pn : P;
        belb[(long)t * KK + j] = P;
        lbb[(long)t * KK + j]  = __logf(P);
        if (j == 0) lzb[t] = on ? __logf(S) : 0.0f;
      }
    }
    #pragma unroll
    for (int k = 0; k < 4; ++k) { emv[k] = emn[k]; bpv[k] = bpn[k]; mv[k] = mn[k]; }
  }
}

// ---------------- K4: A writer (verified r1) ----------------
__global__ __launch_bounds__(256) void a_writer_kernel(
    const float* __restrict__ bp, float* __restrict__ Aout)
{
  long tid  = (long)blockIdx.x * 256 + threadIdx.x;  // 8388608 threads
  long flat = tid * 4;
  int  bt   = (int)(flat >> 8);
  int  rem  = (int)(flat & 255);
  int  r    = rem >> 4;
  int  c0   = rem & 15;
  float p   = bp[bt];
  float eta = fminf(fmaxf(0.02f + 0.33f * p, 0.001f), 0.95f);
  float diag, s;
  if (r == 0)       { diag = 1.0f - eta; s = (1.0f - eta) + eta; }
  else if (r == 15) { diag = 1.0f - RHO; s = RHO + (1.0f - RHO); }
  else { diag = fmaxf((1.0f - eta) - RHO, 0.01f); s = (RHO + diag) + eta; }
  s = fmaxf(s, 1e-8f);
  float inv = 1.0f / s;
  float4 v;
  float* vp = &v.x;
  #pragma unroll
  for (int q = 0; q < 4; ++q) {
    int cc = c0 + q;
    float a = (cc == r) ? diag : (cc == r + 1) ? eta : (cc == r - 1) ? RHO : 0.0f;
    vp[q] = a * inv;
  }
  ((float4*)Aout)[tid] = v;
}

extern "C" void kernel_launch(void* const* d_in, const int* in_sizes, int n_in,
                              void* d_out, int out_size, void* d_ws, size_t ws_size,
                              hipStream_t stream) {
  const float* em = (const float*)d_in[0];
  const float* bp = (const float*)d_in[1];
  const float* mk = (const float*)d_in[2];
  float* out = (float*)d_out;

  const long BTK = (long)BB * TT * KK;
  float* Gbuf = out;                         // stash G in beliefs region
  float* Aout = out + 2 * BTK + (long)BB * TT;
  float* Pst  = Aout;                        // stash P_start in A corner

  hipLaunchKernelGGL(phase1_kernel,   dim3(504),   dim3(256), 0, stream, em, bp, mk, Gbuf);
  hipLaunchKernelGGL(phase2_kernel,   dim3(8),     dim3(256), 0, stream, em, mk, Gbuf, Pst);
  hipLaunchKernelGGL(phase3_kernel,   dim3(128),   dim3(256), 0, stream, em, bp, mk, Pst, out);
  hipLaunchKernelGGL(a_writer_kernel, dim3(32768), dim3(256), 0, stream, bp, Aout);
}